// Round 8
// baseline (466.912 us; speedup 1.0000x reference)
//
#include <hip/hip_runtime.h>
#include <hip/hip_bf16.h>
#include <hip/hip_cooperative_groups.h>
#include <math.h>

namespace cg = cooperative_groups;

// N=64, C=512, T=64, P=2016
// Single cooperative kernel, 512 blocks x 256 threads, 4 phases:
//  P0: wa_part (512u) | xprep (512u) | score_part (256u)   [independent]
//  P1: wprep -> Wb bf16 + Gb (incl. Ab)                     [needs Wpart]
//  P2: fgemm: G[n] = Wb @ xxT[n] + Gb -> FTTb/ALb swizzled  [needs Wb,xxT]
//  P3: pairs: per-pair MFMA GEMM + conv/pool/fc tail        [needs FTTb/ALb]
// Swizzled bf16 operand stores (byte ^ ((row&7)<<4)):
//   FTTb[n]: 32 KB  value B[k][e] at byte (e*256 + k*2) ^ ((e&7)<<4)
//   ALb[i] :  8 KB  value A[o][k] at byte (o*256 + k*2) ^ ((o&7)<<4)
// ws: xxT 4MB | FTTb 2MB | ALb 512KB | Wb 320KB | Wpart 512KB | Gb/part ~3KB

typedef __attribute__((ext_vector_type(8))) short short8;
typedef __attribute__((ext_vector_type(4))) float f32x4;

__device__ __forceinline__ unsigned short f2bf(float f) {
    __hip_bfloat16 h = __float2bfloat16(f);   // RNE
    return *reinterpret_cast<unsigned short*>(&h);
}

__global__ __launch_bounds__(256, 2) void k_mega(
    const float* __restrict__ x, const float* __restrict__ w_conv1d,
    const float* __restrict__ b_conv1d, const float* __restrict__ w_c1,
    const float* __restrict__ b_c1, const float* __restrict__ w_c2,
    const float* __restrict__ b_c2, const float* __restrict__ w_fc1,
    const float* __restrict__ b_fc1, const float* __restrict__ w_fc2,
    const float* __restrict__ b_fc2, const float* __restrict__ w_fc3,
    const float* __restrict__ b_fc3, const float* __restrict__ w_mlp,
    const float* __restrict__ b_mlp,
    unsigned short* __restrict__ xxT, unsigned short* __restrict__ FTTb,
    unsigned short* __restrict__ ALb, unsigned short* __restrict__ Wb,
    float* __restrict__ Wpart, float* __restrict__ Gb,
    float* __restrict__ part, float* __restrict__ out)
{
    __shared__ uint4 smq[2560];        // 40 KB, phase-unioned
    char* sm = (char*)smq;
    cg::grid_group grid = cg::this_grid();
    int bid = blockIdx.x, tid = threadIdx.x;

    // ---------------- P0: wa_part | xprep | score_part ----------------
    for (int u = bid; u < 1280; u += 512) {
        __syncthreads();
        if (u < 512) {
            // wa_part: Wpart[q*64+r][cin]
            int b = u & 127, q = u >> 7;
            int r = b >> 1;
            int cin = (b & 1) * 256 + tid;
            int s = r >> 5, o = r & 31;
            const float* wrow = w_c1 + o * 512 + s;
            const float* wcp  = w_conv1d + cin;
            float acc = 0.f;
            #pragma unroll 8
            for (int c = q * 64; c < q * 64 + 64; ++c)
                acc += wrow[2 * c] * wcp[c * 512];
            Wpart[(q * 64 + r) * 512 + cin] = acc;
        } else if (u < 1024) {
            // xprep: xxT[n][t][c] = bf16(x[n][c][t]) for c-chunk of 64
            int v = u - 512;
            int n = v >> 3, c0 = (v & 7) * 64;
            float* tile = (float*)sm;          // [64][65]
            int cl = tid >> 4, t4 = (tid & 15) * 4;
            const float* xp = x + n * 32768 + c0 * 64;
            #pragma unroll
            for (int pp = 0; pp < 4; ++pp) {
                int c = cl + pp * 16;
                float4 vv = *reinterpret_cast<const float4*>(xp + c * 64 + t4);
                tile[(t4 + 0) * 65 + c] = vv.x; tile[(t4 + 1) * 65 + c] = vv.y;
                tile[(t4 + 2) * 65 + c] = vv.z; tile[(t4 + 3) * 65 + c] = vv.w;
            }
            __syncthreads();
            int tl = tid >> 4, cl4 = (tid & 15) * 4;
            #pragma unroll
            for (int pp = 0; pp < 4; ++pp) {
                int t = tl + pp * 16;
                ushort4 uu;
                uu.x = f2bf(tile[t * 65 + cl4 + 0]);
                uu.y = f2bf(tile[t * 65 + cl4 + 1]);
                uu.z = f2bf(tile[t * 65 + cl4 + 2]);
                uu.w = f2bf(tile[t * 65 + cl4 + 3]);
                *reinterpret_cast<ushort4*>(xxT + n * 32768 + t * 512 + c0 + cl4) = uu;
            }
        } else {
            // score_part: part[n*4+c4]
            int v = u - 1024;
            int n = v >> 2, c4 = v & 3;
            const float4* x4 = reinterpret_cast<const float4*>(x + n * 32768) + c4 * 2048;
            const float4* w4 = reinterpret_cast<const float4*>(w_mlp) + c4 * 2048;
            float acc = 0.f;
            #pragma unroll
            for (int uu = tid, it = 0; it < 8; uu += 256, ++it) {
                float4 a = x4[uu], w = w4[uu];
                acc += a.x * w.x + a.y * w.y + a.z * w.z + a.w * w.w;
            }
            for (int off = 32; off; off >>= 1) acc += __shfl_down(acc, off, 64);
            float* red = (float*)sm;
            if ((tid & 63) == 0) red[tid >> 6] = acc;
            __syncthreads();
            if (tid == 0)
                part[n * 4 + c4] = red[0] + red[1] + red[2] + red[3];
        }
    }
    __threadfence();
    grid.sync();

    // ---------------- P1: wprep (Wb bf16 + Gb incl. Ab) ----------------
    if (bid < 160) {
        int idx = bid * 256 + tid;          // 40960 = 320*512/4
        int m = idx >> 7, c4 = (idx & 127) * 4;
        float4 v;
        if (m < 256) {
            v = *reinterpret_cast<const float4*>(w_conv1d + m * 512 + c4);
        } else {
            const float* p0 = Wpart + (m - 256) * 512 + c4;
            float4 a = *reinterpret_cast<const float4*>(p0);
            float4 b = *reinterpret_cast<const float4*>(p0 + 32768);
            float4 c = *reinterpret_cast<const float4*>(p0 + 65536);
            float4 d = *reinterpret_cast<const float4*>(p0 + 98304);
            v.x = a.x + b.x + c.x + d.x;
            v.y = a.y + b.y + c.y + d.y;
            v.z = a.z + b.z + c.z + d.z;
            v.w = a.w + b.w + c.w + d.w;
        }
        ushort4 uu;
        uu.x = f2bf(v.x); uu.y = f2bf(v.y); uu.z = f2bf(v.z); uu.w = f2bf(v.w);
        *reinterpret_cast<ushort4*>(Wb + m * 512 + c4) = uu;

        if (bid == 0) {
            float* abred = (float*)sm;
            Gb[tid] = b_conv1d[tid];
            int r = tid & 63, q = tid >> 6;
            int s = r >> 5, o = r & 31;
            const float* wr2 = w_c1 + o * 512 + s;
            float a = 0.f;
            #pragma unroll 8
            for (int c = q * 64; c < q * 64 + 64; ++c)
                a += wr2[2 * c] * b_conv1d[c];
            abred[tid] = a;
            __syncthreads();
            if (tid < 64)
                Gb[256 + tid] = abred[tid] + abred[tid + 64]
                              + abred[tid + 128] + abred[tid + 192];
        }
    }
    __threadfence();
    grid.sync();

    // ---------------- P2: fgemm -> FTTb / ALb (swizzled bf16) ----------------
    for (int u = bid; u < 1280; u += 512) {
        int n = u / 20, rem = u - n * 20;
        int mg = rem >> 2, nt = rem & 3;
        int l = tid & 63, w = tid >> 6;
        int m0 = mg * 64 + w * 16;
        int t0 = nt * 16;
        int r15 = l & 15, kg = l >> 4;
        const unsigned short* ap = Wb + (m0 + r15) * 512 + kg * 8;
        const unsigned short* bp = xxT + n * 32768 + (t0 + r15) * 512 + kg * 8;
        f32x4 acc = {0.f, 0.f, 0.f, 0.f};
        #pragma unroll
        for (int ks = 0; ks < 16; ++ks) {
            short8 a = *reinterpret_cast<const short8*>(ap + ks * 32);
            short8 b = *reinterpret_cast<const short8*>(bp + ks * 32);
            acc = __builtin_amdgcn_mfma_f32_16x16x32_bf16(a, b, acc, 0, 0, 0);
        }
        // D: col = l&15 -> t, row = (l>>4)*4 + reg -> m   [m89-verified]
        int t = t0 + r15;
        int mrow = m0 + kg * 4;
        float4 gb = *reinterpret_cast<const float4*>(Gb + mrow);
        float gbv[4] = {gb.x, gb.y, gb.z, gb.w};
        if (m0 < 256) {
            #pragma unroll
            for (int r = 0; r < 4; ++r) {
                int m = mrow + r;
                int e = m & 127, s = m >> 7, kp = s * 64 + t;
                int off = (((e << 8) + (kp << 1)) ^ ((e & 7) << 4)) >> 1;
                FTTb[n * 16384 + off] = f2bf(acc[r] + gbv[r]);
            }
        } else {
            #pragma unroll
            for (int r = 0; r < 4; ++r) {
                int m = mrow + r;
                int rr = m - 256, o = rr & 31, sA = rr >> 5, kp = sA * 64 + t;
                int off = (((o << 8) + (kp << 1)) ^ ((o & 7) << 4)) >> 1;
                ALb[n * 4096 + off] = f2bf(acc[r] + gbv[r]);
            }
        }
    }
    __threadfence();
    grid.sync();

    // ---------------- P3: per-pair MFMA GEMM + tail (+ score sigmoid) --------
    for (int p = bid; p < 2016; p += 512) {
        __syncthreads();               // protect sm reuse across iterations
        int i = 0, rem = p;
        while (rem >= 63 - i) { rem -= 63 - i; ++i; }
        int j = i + 1 + rem;

        if (p == 0 && tid >= 128 && tid < 192) {     // fused score head
            int n = tid - 128;
            float s = part[n * 4] + part[n * 4 + 1] + part[n * 4 + 2]
                    + part[n * 4 + 3] + b_mlp[0];
            out[n] = 1.f / (1.f + expf(-s));
        }

        { // linear staging (swizzle already applied in global layout)
            const uint4* sA = reinterpret_cast<const uint4*>((const char*)ALb + (size_t)i * 8192);
            uint4* dA = reinterpret_cast<uint4*>(sm);
            #pragma unroll
            for (int u = 0; u < 2; ++u) dA[tid + 256 * u] = sA[tid + 256 * u];
            const uint4* sB = reinterpret_cast<const uint4*>((const char*)FTTb + (size_t)j * 32768);
            uint4* dB = reinterpret_cast<uint4*>(sm + 8192);
            #pragma unroll
            for (int u = 0; u < 8; ++u) dB[tid + 256 * u] = sB[tid + 256 * u];
        }
        __syncthreads();

        int l = tid & 63, wid = tid >> 6;
        int col = l & 15;
        int lk16 = (l >> 4) << 4;
        int xr = (col & 7) << 4;
        int oa0 = col, oa1 = col + 16;
        int e0 = wid * 32 + col, e1 = e0 + 16;

        f32x4 acc00 = {0.f,0.f,0.f,0.f}, acc01 = {0.f,0.f,0.f,0.f};
        f32x4 acc10 = {0.f,0.f,0.f,0.f}, acc11 = {0.f,0.f,0.f,0.f};
        #pragma unroll
        for (int ks = 0; ks < 4; ++ks) {
            int kb = ks * 64 + lk16;
            short8 a0 = *reinterpret_cast<const short8*>(sm + (((oa0 << 8) + kb) ^ xr));
            short8 a1 = *reinterpret_cast<const short8*>(sm + (((oa1 << 8) + kb) ^ xr));
            short8 b0 = *reinterpret_cast<const short8*>(sm + 8192 + (((e0 << 8) + kb) ^ xr));
            short8 b1 = *reinterpret_cast<const short8*>(sm + 8192 + (((e1 << 8) + kb) ^ xr));
            acc00 = __builtin_amdgcn_mfma_f32_16x16x32_bf16(a0, b0, acc00, 0, 0, 0);
            acc01 = __builtin_amdgcn_mfma_f32_16x16x32_bf16(a0, b1, acc01, 0, 0, 0);
            acc10 = __builtin_amdgcn_mfma_f32_16x16x32_bf16(a1, b0, acc10, 0, 0, 0);
            acc11 = __builtin_amdgcn_mfma_f32_16x16x32_bf16(a1, b1, acc11, 0, 0, 0);
        }
        __syncthreads();   // staging no longer needed; write H over it

        // D layout: col = lane&15, row = (lane>>4)*4 + reg   [m89-verified]
        float* H = (float*)sm;             // H[32][128] f32
        int rowbase = (l >> 4) * 4;
        #pragma unroll
        for (int r4 = 0; r4 < 4; ++r4) {
            int o0 = rowbase + r4, o1 = o0 + 16;
            float bb0 = b_c1[o0], bb1 = b_c1[o1];
            H[o0 * 128 + e0] = acc00[r4] + bb0;
            H[o0 * 128 + e1] = acc01[r4] + bb0;
            H[o1 * 128 + e0] = acc10[r4] + bb1;
            H[o1 * 128 + e1] = acc11[r4] + bb1;
        }
        __syncthreads();

        // pool1
        float* PL = (float*)(sm + 16384);
        for (int idx = tid; idx < 1024; idx += 256) {
            int o = idx >> 5, h2 = (idx >> 1) & 15, w2 = idx & 1;
            const float* hp = H + o * 128 + h2 * 8 + w2 * 2;
            PL[o * 32 + h2 * 2 + w2] =
                fmaxf(fmaxf(hp[0], hp[1]), fmaxf(hp[4], hp[5]));
        }
        __syncthreads();

        // conv2
        float* C2 = (float*)(sm + 20480);
        {
            int o2 = tid >> 5, pos = tid & 31;
            float a2 = b_c2[o2];
            #pragma unroll 8
            for (int o = 0; o < 32; ++o) a2 += w_c2[o2 * 32 + o] * PL[o * 32 + pos];
            C2[o2 * 32 + pos] = a2;
        }
        __syncthreads();

        // pool2
        float* V = (float*)(sm + 21504);
        if (tid < 64) {
            int o2 = tid >> 3, h3 = tid & 7;
            const float* cp = C2 + o2 * 32 + h3 * 4;
            V[tid] = fmaxf(fmaxf(cp[0], cp[1]), fmaxf(cp[2], cp[3]));
        }
        __syncthreads();

        float* R1 = (float*)(sm + 21760);
        if (tid < 32) {
            float a = b_fc1[tid];
            const float* wr = w_fc1 + tid * 64;
            #pragma unroll 8
            for (int u = 0; u < 64; ++u) a += wr[u] * V[u];
            R1[tid] = fmaxf(a, 0.f);
        }
        __syncthreads();

        float* R2 = (float*)(sm + 21888);
        if (tid < 8) {
            float a = b_fc2[tid];
            #pragma unroll 8
            for (int u = 0; u < 32; ++u) a += w_fc2[tid * 32 + u] * R1[u];
            R2[tid] = fmaxf(a, 0.f);
        }
        __syncthreads();

        if (tid == 0) {
            float a = b_fc3[0];
            #pragma unroll
            for (int u = 0; u < 8; ++u) a += w_fc3[u] * R2[u];
            out[64 + p] = 1.f / (1.f + expf(-a));
        }
    }
}

extern "C" void kernel_launch(void* const* d_in, const int* in_sizes, int n_in,
                              void* d_out, int out_size, void* d_ws, size_t ws_size,
                              hipStream_t stream) {
    const float* x        = (const float*)d_in[0];
    const float* w_conv1d = (const float*)d_in[1];
    const float* b_conv1d = (const float*)d_in[2];
    const float* w_c1     = (const float*)d_in[3];
    const float* b_c1     = (const float*)d_in[4];
    const float* w_c2     = (const float*)d_in[5];
    const float* b_c2     = (const float*)d_in[6];
    const float* w_fc1    = (const float*)d_in[7];
    const float* b_fc1    = (const float*)d_in[8];
    const float* w_fc2    = (const float*)d_in[9];
    const float* b_fc2    = (const float*)d_in[10];
    const float* w_fc3    = (const float*)d_in[11];
    const float* b_fc3    = (const float*)d_in[12];
    const float* w_mlp    = (const float*)d_in[13];
    const float* b_mlp    = (const float*)d_in[14];
    float* out = (float*)d_out;

    char* base = (char*)d_ws;
    unsigned short* xxT   = (unsigned short*)(base);                  // 4 MB
    unsigned short* FTTb  = (unsigned short*)(base + 4194304);        // 2 MB
    unsigned short* ALb   = (unsigned short*)(base + 6291456);        // 512 KB
    unsigned short* Wb    = (unsigned short*)(base + 6815744);        // 320 KB
    float*          Wpart = (float*)(base + 7143424);                 // 512 KB
    float*          Gb    = (float*)(base + 7667712);                 // 1280 B
    float*          part  = (float*)(base + 7669760);                 // 1 KB
    // total ~7.3 MB (9 MB proven safe)

    void* args[] = {
        (void*)&x, (void*)&w_conv1d, (void*)&b_conv1d, (void*)&w_c1,
        (void*)&b_c1, (void*)&w_c2, (void*)&b_c2, (void*)&w_fc1,
        (void*)&b_fc1, (void*)&w_fc2, (void*)&b_fc2, (void*)&w_fc3,
        (void*)&b_fc3, (void*)&w_mlp, (void*)&b_mlp,
        (void*)&xxT, (void*)&FTTb, (void*)&ALb, (void*)&Wb,
        (void*)&Wpart, (void*)&Gb, (void*)&part, (void*)&out
    };
    hipLaunchCooperativeKernel((const void*)k_mega, dim3(512), dim3(256),
                               args, 0, stream);
}

// Round 9
// 135.333 us; speedup vs baseline: 3.4501x; 3.4501x over previous
//
#include <hip/hip_runtime.h>
#include <hip/hip_bf16.h>
#include <math.h>

// N=64, C=512, T=64, P=2016
// 3-kernel pipeline (round-7 math, bit-identical; 6 launches -> 3):
//  k_prep  (1025 blocks): Wb rows0-255 bf16 | Wa->Wb rows 256-319 | Gb+Ab
//                         | xprep (xxT) | score_part        [all independent]
//  k_fgemm (64,5,4): G[n] = Wb @ xxT[n] + Gb -> FTTb/ALb (swizzled bf16)
//  k_pairs (2016): per-pair MFMA GEMM + conv/pool/fc tail + fused sigmoid
// Swizzled bf16 operand stores (byte ^ ((row&7)<<4)):
//   FTTb[n]: 32 KB  value B[k][e] at byte (e*256 + k*2) ^ ((e&7)<<4)
//   ALb[i] :  8 KB  value A[o][k] at byte (o*256 + k*2) ^ ((o&7)<<4)
// ws: xxT 4MB | FTTb 2MB | ALb 512KB | Wb 320KB | Gb/part ~3KB  (~6.8 MB)

typedef __attribute__((ext_vector_type(8))) short short8;
typedef __attribute__((ext_vector_type(4))) float f32x4;

__device__ __forceinline__ unsigned short f2bf(float f) {
    __hip_bfloat16 h = __float2bfloat16(f);   // RNE
    return *reinterpret_cast<unsigned short*>(&h);
}

// ---------------- k_prep: all independent prep in one launch ----------------
// units: [0,128)   Wb rows 0..255 (bf16 convert of w_conv1d)
//        [128,256) Wa rows 256..319 of Wb (4-way q-partials, ordered sum)
//        256       Gb (bias) + Ab
//        [257,769) xprep: xxT[n][t][c] = bf16(x[n][c][t])
//        [769,1025) score_part
__global__ __launch_bounds__(256) void k_prep(
    const float* __restrict__ x, const float* __restrict__ w_conv1d,
    const float* __restrict__ b_conv1d, const float* __restrict__ w_c1,
    const float* __restrict__ w_mlp,
    unsigned short* __restrict__ xxT, unsigned short* __restrict__ Wb,
    float* __restrict__ Gb, float* __restrict__ part)
{
    __shared__ float sf[64 * 65];      // xprep tile / abred / red
    int u = blockIdx.x, tid = threadIdx.x;

    if (u < 128) {
        // Wb rows 0..255: bf16 convert, 4 floats/thread
        int idx = u * 256 + tid;
        int m = idx >> 7, c4 = (idx & 127) * 4;
        float4 v = *reinterpret_cast<const float4*>(w_conv1d + m * 512 + c4);
        ushort4 uu;
        uu.x = f2bf(v.x); uu.y = f2bf(v.y); uu.z = f2bf(v.z); uu.w = f2bf(v.w);
        *reinterpret_cast<ushort4*>(Wb + m * 512 + c4) = uu;
    } else if (u < 256) {
        // Wa[r][cin] -> Wb[256+r][cin]; same q-split + ordered sum as before
        int b = u - 128;
        int r = b >> 1;
        int cin = (b & 1) * 256 + tid;
        int s = r >> 5, o = r & 31;
        const float* wrow = w_c1 + o * 512 + s;       // block-uniform
        const float* wcp  = w_conv1d + cin;           // coalesced
        float pq[4];
        #pragma unroll
        for (int q = 0; q < 4; ++q) {
            float acc = 0.f;
            #pragma unroll 8
            for (int c = q * 64; c < q * 64 + 64; ++c)
                acc += wrow[2 * c] * wcp[c * 512];
            pq[q] = acc;
        }
        float v = ((pq[0] + pq[1]) + pq[2]) + pq[3];  // == Wpart-path order
        Wb[(256 + r) * 512 + cin] = f2bf(v);
    } else if (u == 256) {
        // Gb bias + Ab (same structure as old wprep block 0)
        float* abred = sf;
        Gb[tid] = b_conv1d[tid];
        int r = tid & 63, q = tid >> 6;
        int s = r >> 5, o = r & 31;
        const float* wr2 = w_c1 + o * 512 + s;
        float a = 0.f;
        #pragma unroll 8
        for (int c = q * 64; c < q * 64 + 64; ++c)
            a += wr2[2 * c] * b_conv1d[c];
        abred[tid] = a;
        __syncthreads();
        if (tid < 64)
            Gb[256 + tid] = abred[tid] + abred[tid + 64]
                          + abred[tid + 128] + abred[tid + 192];
    } else if (u < 769) {
        // xprep (verbatim, tile in sf)
        int v = u - 257;
        int n = v >> 3, c0 = (v & 7) * 64;
        float* tile = sf;                  // [64][65]
        int cl = tid >> 4, t4 = (tid & 15) * 4;
        const float* xp = x + n * 32768 + c0 * 64;
        #pragma unroll
        for (int pp = 0; pp < 4; ++pp) {
            int c = cl + pp * 16;
            float4 vv = *reinterpret_cast<const float4*>(xp + c * 64 + t4);
            tile[(t4 + 0) * 65 + c] = vv.x; tile[(t4 + 1) * 65 + c] = vv.y;
            tile[(t4 + 2) * 65 + c] = vv.z; tile[(t4 + 3) * 65 + c] = vv.w;
        }
        __syncthreads();
        int tl = tid >> 4, cl4 = (tid & 15) * 4;
        #pragma unroll
        for (int pp = 0; pp < 4; ++pp) {
            int t = tl + pp * 16;
            ushort4 uu;
            uu.x = f2bf(tile[t * 65 + cl4 + 0]);
            uu.y = f2bf(tile[t * 65 + cl4 + 1]);
            uu.z = f2bf(tile[t * 65 + cl4 + 2]);
            uu.w = f2bf(tile[t * 65 + cl4 + 3]);
            *reinterpret_cast<ushort4*>(xxT + n * 32768 + t * 512 + c0 + cl4) = uu;
        }
    } else {
        // score_part (verbatim)
        int v = u - 769;
        int n = v >> 2, c4 = v & 3;
        const float4* x4 = reinterpret_cast<const float4*>(x + n * 32768) + c4 * 2048;
        const float4* w4 = reinterpret_cast<const float4*>(w_mlp) + c4 * 2048;
        float acc = 0.f;
        for (int uu = tid; uu < 2048; uu += 256) {
            float4 a = x4[uu], w = w4[uu];
            acc += a.x * w.x + a.y * w.y + a.z * w.z + a.w * w.w;
        }
        for (int off = 32; off; off >>= 1) acc += __shfl_down(acc, off, 64);
        float* red = sf;
        if ((tid & 63) == 0) red[tid >> 6] = acc;
        __syncthreads();
        if (tid == 0)
            part[n * 4 + c4] = red[0] + red[1] + red[2] + red[3];
    }
}

// ---------------- k_fgemm: G = Wb @ x + Gb -> FTTb / ALb (swizzled bf16) ---
// grid (64 n, 5 mg, 4 nt); wave w: m-tile = mg*64 + w*16, t-tile = nt*16
__global__ __launch_bounds__(256) void k_fgemm(
    const unsigned short* __restrict__ Wb, const unsigned short* __restrict__ xxT,
    const float* __restrict__ Gb, unsigned short* __restrict__ FTTb,
    unsigned short* __restrict__ ALb)
{
    int n = blockIdx.x, mg = blockIdx.y, nt = blockIdx.z;
    int tid = threadIdx.x, l = tid & 63, w = tid >> 6;
    int m0 = mg * 64 + w * 16;
    int t0 = nt * 16;
    int r15 = l & 15, kg = l >> 4;
    const unsigned short* ap = Wb + (m0 + r15) * 512 + kg * 8;
    const unsigned short* bp = xxT + n * 32768 + (t0 + r15) * 512 + kg * 8;
    f32x4 acc = {0.f, 0.f, 0.f, 0.f};
    #pragma unroll
    for (int ks = 0; ks < 16; ++ks) {
        short8 a = *reinterpret_cast<const short8*>(ap + ks * 32);
        short8 b = *reinterpret_cast<const short8*>(bp + ks * 32);
        acc = __builtin_amdgcn_mfma_f32_16x16x32_bf16(a, b, acc, 0, 0, 0);
    }
    // D: col = l&15 -> t, row = (l>>4)*4 + reg -> m   [m89-verified]
    int t = t0 + r15;
    int mrow = m0 + kg * 4;
    float4 gb = *reinterpret_cast<const float4*>(Gb + mrow);
    float gbv[4] = {gb.x, gb.y, gb.z, gb.w};
    if (m0 < 256) {
        #pragma unroll
        for (int r = 0; r < 4; ++r) {
            int m = mrow + r;
            int e = m & 127, s = m >> 7, kp = s * 64 + t;
            int off = (((e << 8) + (kp << 1)) ^ ((e & 7) << 4)) >> 1;
            FTTb[n * 16384 + off] = f2bf(acc[r] + gbv[r]);
        }
    } else {
        #pragma unroll
        for (int r = 0; r < 4; ++r) {
            int m = mrow + r;
            int rr = m - 256, o = rr & 31, sA = rr >> 5, kp = sA * 64 + t;
            int off = (((o << 8) + (kp << 1)) ^ ((o & 7) << 4)) >> 1;
            ALb[n * 4096 + off] = f2bf(acc[r] + gbv[r]);
        }
    }
}

// ---------------- k_pairs: per-pair MFMA GEMM + tail (+ fused sigmoid) ------
__global__ __launch_bounds__(256) void k_pairs(
    const char* __restrict__ FTTb, const char* __restrict__ ALb,
    const float* __restrict__ b_c1, const float* __restrict__ w_c2,
    const float* __restrict__ b_c2, const float* __restrict__ w_fc1,
    const float* __restrict__ b_fc1, const float* __restrict__ w_fc2,
    const float* __restrict__ b_fc2, const float* __restrict__ w_fc3,
    const float* __restrict__ b_fc3, const float* __restrict__ part,
    const float* __restrict__ bm, float* __restrict__ out)
{
    __shared__ uint4 smq[2560];        // 40 KB: A bf16 [0,8K), B bf16 [8K,40K)
    char* sm = (char*)smq;
    int p = blockIdx.x;
    int i = 0, rem = p;
    while (rem >= 63 - i) { rem -= 63 - i; ++i; }
    int j = i + 1 + rem;
    int tid = threadIdx.x;

    // fused score head: block 0, lanes 128..191, pre-barrier
    if (p == 0 && tid >= 128 && tid < 192) {
        int n = tid - 128;
        float s = part[n * 4] + part[n * 4 + 1] + part[n * 4 + 2]
                + part[n * 4 + 3] + bm[0];
        out[n] = 1.f / (1.f + expf(-s));
    }

    { // linear staging (swizzle already applied in global layout)
        const uint4* sA = reinterpret_cast<const uint4*>(ALb + (size_t)i * 8192);
        uint4* dA = reinterpret_cast<uint4*>(sm);
        #pragma unroll
        for (int u = 0; u < 2; ++u) dA[tid + 256 * u] = sA[tid + 256 * u];
        const uint4* sB = reinterpret_cast<const uint4*>(FTTb + (size_t)j * 32768);
        uint4* dB = reinterpret_cast<uint4*>(sm + 8192);
        #pragma unroll
        for (int u = 0; u < 8; ++u) dB[tid + 256 * u] = sB[tid + 256 * u];
    }
    __syncthreads();

    int l = tid & 63, wid = tid >> 6;
    int col = l & 15;
    int lk16 = (l >> 4) << 4;          // byte offset of this lane's k-subchunk
    int xr = (col & 7) << 4;           // XOR swizzle (row&7 == col&7 here)
    int oa0 = col, oa1 = col + 16;
    int e0 = wid * 32 + col, e1 = e0 + 16;

    f32x4 acc00 = {0.f,0.f,0.f,0.f}, acc01 = {0.f,0.f,0.f,0.f};
    f32x4 acc10 = {0.f,0.f,0.f,0.f}, acc11 = {0.f,0.f,0.f,0.f};
    #pragma unroll
    for (int ks = 0; ks < 4; ++ks) {
        int kb = ks * 64 + lk16;
        short8 a0 = *reinterpret_cast<const short8*>(sm + (((oa0 << 8) + kb) ^ xr));
        short8 a1 = *reinterpret_cast<const short8*>(sm + (((oa1 << 8) + kb) ^ xr));
        short8 b0 = *reinterpret_cast<const short8*>(sm + 8192 + (((e0 << 8) + kb) ^ xr));
        short8 b1 = *reinterpret_cast<const short8*>(sm + 8192 + (((e1 << 8) + kb) ^ xr));
        acc00 = __builtin_amdgcn_mfma_f32_16x16x32_bf16(a0, b0, acc00, 0, 0, 0);
        acc01 = __builtin_amdgcn_mfma_f32_16x16x32_bf16(a0, b1, acc01, 0, 0, 0);
        acc10 = __builtin_amdgcn_mfma_f32_16x16x32_bf16(a1, b0, acc10, 0, 0, 0);
        acc11 = __builtin_amdgcn_mfma_f32_16x16x32_bf16(a1, b1, acc11, 0, 0, 0);
    }
    __syncthreads();   // staging no longer needed; write H over it

    // D layout: col = lane&15, row = (lane>>4)*4 + reg   [m89-verified]
    float* H = (float*)sm;             // H[32][128] f32, 16 KB
    int rowbase = (l >> 4) * 4;
    #pragma unroll
    for (int r4 = 0; r4 < 4; ++r4) {
        int o0 = rowbase + r4, o1 = o0 + 16;
        float bb0 = b_c1[o0], bb1 = b_c1[o1];
        H[o0 * 128 + e0] = acc00[r4] + bb0;
        H[o0 * 128 + e1] = acc01[r4] + bb0;
        H[o1 * 128 + e0] = acc10[r4] + bb1;
        H[o1 * 128 + e1] = acc11[r4] + bb1;
    }
    __syncthreads();

    // pool1
    float* PL = (float*)(sm + 16384);  // 1024 f
    for (int idx = tid; idx < 1024; idx += 256) {
        int o = idx >> 5, h2 = (idx >> 1) & 15, w2 = idx & 1;
        const float* hp = H + o * 128 + h2 * 8 + w2 * 2;
        PL[o * 32 + h2 * 2 + w2] =
            fmaxf(fmaxf(hp[0], hp[1]), fmaxf(hp[4], hp[5]));
    }
    __syncthreads();

    // conv2
    float* C2 = (float*)(sm + 20480);  // 256 f
    {
        int o2 = tid >> 5, pos = tid & 31;
        float a2 = b_c2[o2];
        #pragma unroll 8
        for (int o = 0; o < 32; ++o) a2 += w_c2[o2 * 32 + o] * PL[o * 32 + pos];
        C2[o2 * 32 + pos] = a2;
    }
    __syncthreads();

    // pool2
    float* V = (float*)(sm + 21504);   // 64 f
    if (tid < 64) {
        int o2 = tid >> 3, h3 = tid & 7;
        const float* cp = C2 + o2 * 32 + h3 * 4;
        V[tid] = fmaxf(fmaxf(cp[0], cp[1]), fmaxf(cp[2], cp[3]));
    }
    __syncthreads();

    float* R1 = (float*)(sm + 21760);  // 32 f
    if (tid < 32) {
        float a = b_fc1[tid];
        const float* wr = w_fc1 + tid * 64;
        #pragma unroll 8
        for (int u = 0; u < 64; ++u) a += wr[u] * V[u];
        R1[tid] = fmaxf(a, 0.f);
    }
    __syncthreads();

    float* R2 = (float*)(sm + 21888);  // 8 f
    if (tid < 8) {
        float a = b_fc2[tid];
        #pragma unroll 8
        for (int u = 0; u < 32; ++u) a += w_fc2[tid * 32 + u] * R1[u];
        R2[tid] = fmaxf(a, 0.f);
    }
    __syncthreads();

    if (tid == 0) {
        float a = b_fc3[0];
        #pragma unroll
        for (int u = 0; u < 8; ++u) a += w_fc3[u] * R2[u];
        out[64 + p] = 1.f / (1.f + expf(-a));
    }
}

extern "C" void kernel_launch(void* const* d_in, const int* in_sizes, int n_in,
                              void* d_out, int out_size, void* d_ws, size_t ws_size,
                              hipStream_t stream) {
    const float* x        = (const float*)d_in[0];
    const float* w_conv1d = (const float*)d_in[1];
    const float* b_conv1d = (const float*)d_in[2];
    const float* w_c1     = (const float*)d_in[3];
    const float* b_c1     = (const float*)d_in[4];
    const float* w_c2     = (const float*)d_in[5];
    const float* b_c2     = (const float*)d_in[6];
    const float* w_fc1    = (const float*)d_in[7];
    const float* b_fc1    = (const float*)d_in[8];
    const float* w_fc2    = (const float*)d_in[9];
    const float* b_fc2    = (const float*)d_in[10];
    const float* w_fc3    = (const float*)d_in[11];
    const float* b_fc3    = (const float*)d_in[12];
    const float* w_mlp    = (const float*)d_in[13];
    const float* b_mlp    = (const float*)d_in[14];
    float* out = (float*)d_out;

    char* base = (char*)d_ws;
    unsigned short* xxT  = (unsigned short*)(base);                  // 4 MB
    unsigned short* FTTb = (unsigned short*)(base + 4194304);        // 2 MB
    unsigned short* ALb  = (unsigned short*)(base + 6291456);        // 512 KB
    unsigned short* Wb   = (unsigned short*)(base + 6815744);        // 320 KB
    float*          Gb   = (float*)(base + 7143424);                 // 1280 B
    float*          part = (float*)(base + 7145472);                 // 1 KB
    // total ~6.8 MB (9 MB proven safe)

    hipLaunchKernelGGL(k_prep, dim3(1025), dim3(256), 0, stream,
                       x, w_conv1d, b_conv1d, w_c1, w_mlp,
                       xxT, Wb, Gb, part);
    hipLaunchKernelGGL(k_fgemm, dim3(64, 5, 4), dim3(256), 0, stream,
                       Wb, xxT, Gb, FTTb, ALb);
    hipLaunchKernelGGL(k_pairs, dim3(2016), dim3(256), 0, stream,
                       (const char*)FTTb, (const char*)ALb,
                       b_c1, w_c2, b_c2, w_fc1, b_fc1,
                       w_fc2, b_fc2, w_fc3, b_fc3, part, b_mlp, out);
}

// Round 10
// 118.729 us; speedup vs baseline: 3.9326x; 1.1398x over previous
//
#include <hip/hip_runtime.h>
#include <hip/hip_bf16.h>
#include <math.h>

// N=64, C=512, T=64, P=2016
// 3-kernel pipeline (bit-identical math to round 9):
//  k_prep  (1025 blocks): Wbf (fragment-packed bf16 W', 320x512) | Gb+Ab
//                         | xprep -> xxTf (fragment-packed bf16 x^T) | score_part
//  k_fgemm (64,5,4): G[n] = W' @ x[n] + Gb -> FTTb/ALb (swizzled bf16)
//      operands read fragment-packed: lane l reads shorts at
//      ((mt*16+kc)*64 + l)*8  -> fully coalesced 1KB per fragment load
//  k_pairs (2016): per-pair MFMA GEMM + conv/pool/fc tail + fused sigmoid
// Fragment packing (lane l = k8*16 + r15 for mfma_16x16x32_bf16):
//   value (row m, k) lives at ((mt*16+kc)*64 + ((k>>3)&3)*16 + (m&15))*8 + (k&7)
//   mt = m>>4, kc = k>>5.  Same for x^T with rows t.
// Swizzled bf16 pair-operand stores (byte ^ ((row&7)<<4)):
//   FTTb[n]: 32 KB  value B[k][e] at byte (e*256 + k*2) ^ ((e&7)<<4)
//   ALb[i] :  8 KB  value A[o][k] at byte (o*256 + k*2) ^ ((o&7)<<4)
// ws: xxTf 4MB | FTTb 2MB | ALb 512KB | Wbf 320KB | Gb/part ~3KB  (~6.8 MB)

typedef __attribute__((ext_vector_type(8))) short short8;
typedef __attribute__((ext_vector_type(4))) float f32x4;

__device__ __forceinline__ unsigned short f2bf(float f) {
    __hip_bfloat16 h = __float2bfloat16(f);   // RNE
    return *reinterpret_cast<unsigned short*>(&h);
}

// ---------------- k_prep: all independent prep in one launch ----------------
// units: [0,128)   w_conv1d rows 0..255 -> Wbf (packed bf16)
//        [128,256) Wa rows 256..319 -> Wbf (4-way q-partials, ordered sum)
//        256       Gb (bias) + Ab
//        [257,769) xprep: x[n] -> xxTf (packed bf16 of x^T)
//        [769,1025) score_part
__global__ __launch_bounds__(256) void k_prep(
    const float* __restrict__ x, const float* __restrict__ w_conv1d,
    const float* __restrict__ b_conv1d, const float* __restrict__ w_c1,
    const float* __restrict__ w_mlp,
    unsigned short* __restrict__ xxTf, unsigned short* __restrict__ Wbf,
    float* __restrict__ Gb, float* __restrict__ part)
{
    __shared__ float sf[64 * 65];      // xprep tile / abred / red
    int u = blockIdx.x, tid = threadIdx.x;

    if (u < 128) {
        // Wbf rows 0..255: bf16 convert, 4 floats/thread, packed store
        int idx = u * 256 + tid;
        int m = idx >> 7, c4 = (idx & 127) * 4;
        float4 v = *reinterpret_cast<const float4*>(w_conv1d + m * 512 + c4);
        ushort4 uu;
        uu.x = f2bf(v.x); uu.y = f2bf(v.y); uu.z = f2bf(v.z); uu.w = f2bf(v.w);
        int mt = m >> 4, r15 = m & 15;
        int kc = c4 >> 5, k8 = (c4 >> 3) & 3, rem = c4 & 7;
        *reinterpret_cast<ushort4*>(
            Wbf + ((mt * 16 + kc) * 64 + k8 * 16 + r15) * 8 + rem) = uu;
    } else if (u < 256) {
        // Wa[r][cin] -> Wbf rows 256..319; same q-split + ordered sum
        int b = u - 128;
        int r = b >> 1;
        int cin = (b & 1) * 256 + tid;
        int s = r >> 5, o = r & 31;
        const float* wrow = w_c1 + o * 512 + s;       // block-uniform
        const float* wcp  = w_conv1d + cin;           // coalesced
        float pq[4];
        #pragma unroll
        for (int q = 0; q < 4; ++q) {
            float acc = 0.f;
            #pragma unroll 8
            for (int c = q * 64; c < q * 64 + 64; ++c)
                acc += wrow[2 * c] * wcp[c * 512];
            pq[q] = acc;
        }
        float v = ((pq[0] + pq[1]) + pq[2]) + pq[3];
        int m = 256 + r;
        int mt = m >> 4, r15 = m & 15;
        int kc = cin >> 5, k8 = (cin >> 3) & 3, rem = cin & 7;
        Wbf[((mt * 16 + kc) * 64 + k8 * 16 + r15) * 8 + rem] = f2bf(v);
    } else if (u == 256) {
        // Gb bias + Ab
        float* abred = sf;
        Gb[tid] = b_conv1d[tid];
        int r = tid & 63, q = tid >> 6;
        int s = r >> 5, o = r & 31;
        const float* wr2 = w_c1 + o * 512 + s;
        float a = 0.f;
        #pragma unroll 8
        for (int c = q * 64; c < q * 64 + 64; ++c)
            a += wr2[2 * c] * b_conv1d[c];
        abred[tid] = a;
        __syncthreads();
        if (tid < 64)
            Gb[256 + tid] = abred[tid] + abred[tid + 64]
                          + abred[tid + 128] + abred[tid + 192];
    } else if (u < 769) {
        // xprep: transpose then packed bf16 store
        int v = u - 257;
        int n = v >> 3, c0 = (v & 7) * 64;
        float* tile = sf;                  // [64][65]
        int cl = tid >> 4, t4 = (tid & 15) * 4;
        const float* xp = x + n * 32768 + c0 * 64;
        #pragma unroll
        for (int pp = 0; pp < 4; ++pp) {
            int c = cl + pp * 16;
            float4 vv = *reinterpret_cast<const float4*>(xp + c * 64 + t4);
            tile[(t4 + 0) * 65 + c] = vv.x; tile[(t4 + 1) * 65 + c] = vv.y;
            tile[(t4 + 2) * 65 + c] = vv.z; tile[(t4 + 3) * 65 + c] = vv.w;
        }
        __syncthreads();
        int tl = tid >> 4, cl4 = (tid & 15) * 4;
        int c = c0 + cl4;
        int kc = c >> 5, k8 = (c >> 3) & 3, rem = c & 7;
        #pragma unroll
        for (int pp = 0; pp < 4; ++pp) {
            int t = tl + pp * 16;          // tt = pp, r15 = tl
            ushort4 uu;
            uu.x = f2bf(tile[t * 65 + cl4 + 0]);
            uu.y = f2bf(tile[t * 65 + cl4 + 1]);
            uu.z = f2bf(tile[t * 65 + cl4 + 2]);
            uu.w = f2bf(tile[t * 65 + cl4 + 3]);
            *reinterpret_cast<ushort4*>(
                xxTf + n * 32768 + ((pp * 16 + kc) * 64 + k8 * 16 + tl) * 8 + rem) = uu;
        }
    } else {
        // score_part
        int v = u - 769;
        int n = v >> 2, c4 = v & 3;
        const float4* x4 = reinterpret_cast<const float4*>(x + n * 32768) + c4 * 2048;
        const float4* w4 = reinterpret_cast<const float4*>(w_mlp) + c4 * 2048;
        float acc = 0.f;
        for (int uu = tid; uu < 2048; uu += 256) {
            float4 a = x4[uu], w = w4[uu];
            acc += a.x * w.x + a.y * w.y + a.z * w.z + a.w * w.w;
        }
        for (int off = 32; off; off >>= 1) acc += __shfl_down(acc, off, 64);
        float* red = sf;
        if ((tid & 63) == 0) red[tid >> 6] = acc;
        __syncthreads();
        if (tid == 0)
            part[n * 4 + c4] = red[0] + red[1] + red[2] + red[3];
    }
}

// ---------------- k_fgemm: G = W' @ x + Gb -> FTTb / ALb (swizzled bf16) ---
// grid (64 n, 5 mg, 4 nt); wave w: m-tile mt = mg*4+w, t-tile tt = nt
// fragment-packed reads: lane l loads 16B at ((mt*16+kc)*64 + l)*8 shorts
__global__ __launch_bounds__(256) void k_fgemm(
    const unsigned short* __restrict__ Wbf, const unsigned short* __restrict__ xxTf,
    const float* __restrict__ Gb, unsigned short* __restrict__ FTTb,
    unsigned short* __restrict__ ALb)
{
    int n = blockIdx.x, mg = blockIdx.y, nt = blockIdx.z;
    int tid = threadIdx.x, l = tid & 63, w = tid >> 6;
    int mt = mg * 4 + w;
    int m0 = mt * 16;
    int t0 = nt * 16;
    int r15 = l & 15, kg = l >> 4;
    const unsigned short* ap = Wbf + (size_t)mt * 16 * 512 + l * 8;
    const unsigned short* bp = xxTf + (size_t)n * 32768 + (size_t)nt * 16 * 512 + l * 8;
    f32x4 acc = {0.f, 0.f, 0.f, 0.f};
    #pragma unroll
    for (int ks = 0; ks < 16; ++ks) {
        short8 a = *reinterpret_cast<const short8*>(ap + ks * 512);
        short8 b = *reinterpret_cast<const short8*>(bp + ks * 512);
        acc = __builtin_amdgcn_mfma_f32_16x16x32_bf16(a, b, acc, 0, 0, 0);
    }
    // D: col = l&15 -> t, row = (l>>4)*4 + reg -> m   [m89-verified]
    int t = t0 + r15;
    int mrow = m0 + kg * 4;
    float4 gb = *reinterpret_cast<const float4*>(Gb + mrow);
    float gbv[4] = {gb.x, gb.y, gb.z, gb.w};
    if (m0 < 256) {
        #pragma unroll
        for (int r = 0; r < 4; ++r) {
            int m = mrow + r;
            int e = m & 127, s = m >> 7, kp = s * 64 + t;
            int off = (((e << 8) + (kp << 1)) ^ ((e & 7) << 4)) >> 1;
            FTTb[n * 16384 + off] = f2bf(acc[r] + gbv[r]);
        }
    } else {
        #pragma unroll
        for (int r = 0; r < 4; ++r) {
            int m = mrow + r;
            int rr = m - 256, o = rr & 31, sA = rr >> 5, kp = sA * 64 + t;
            int off = (((o << 8) + (kp << 1)) ^ ((o & 7) << 4)) >> 1;
            ALb[n * 4096 + off] = f2bf(acc[r] + gbv[r]);
        }
    }
}

// ---------------- k_pairs: per-pair MFMA GEMM + tail (+ fused sigmoid) ------
__global__ __launch_bounds__(256) void k_pairs(
    const char* __restrict__ FTTb, const char* __restrict__ ALb,
    const float* __restrict__ b_c1, const float* __restrict__ w_c2,
    const float* __restrict__ b_c2, const float* __restrict__ w_fc1,
    const float* __restrict__ b_fc1, const float* __restrict__ w_fc2,
    const float* __restrict__ b_fc2, const float* __restrict__ w_fc3,
    const float* __restrict__ b_fc3, const float* __restrict__ part,
    const float* __restrict__ bm, float* __restrict__ out)
{
    __shared__ uint4 smq[2560];        // 40 KB: A bf16 [0,8K), B bf16 [8K,40K)
    char* sm = (char*)smq;
    int p = blockIdx.x;
    int i = 0, rem = p;
    while (rem >= 63 - i) { rem -= 63 - i; ++i; }
    int j = i + 1 + rem;
    int tid = threadIdx.x;

    // fused score head: block 0, lanes 128..191, pre-barrier
    if (p == 0 && tid >= 128 && tid < 192) {
        int n = tid - 128;
        float s = part[n * 4] + part[n * 4 + 1] + part[n * 4 + 2]
                + part[n * 4 + 3] + bm[0];
        out[n] = 1.f / (1.f + expf(-s));
    }

    { // linear staging (swizzle already applied in global layout)
        const uint4* sA = reinterpret_cast<const uint4*>(ALb + (size_t)i * 8192);
        uint4* dA = reinterpret_cast<uint4*>(sm);
        #pragma unroll
        for (int u = 0; u < 2; ++u) dA[tid + 256 * u] = sA[tid + 256 * u];
        const uint4* sB = reinterpret_cast<const uint4*>(FTTb + (size_t)j * 32768);
        uint4* dB = reinterpret_cast<uint4*>(sm + 8192);
        #pragma unroll
        for (int u = 0; u < 8; ++u) dB[tid + 256 * u] = sB[tid + 256 * u];
    }
    __syncthreads();

    int l = tid & 63, wid = tid >> 6;
    int col = l & 15;
    int lk16 = (l >> 4) << 4;          // byte offset of this lane's k-subchunk
    int xr = (col & 7) << 4;           // XOR swizzle (row&7 == col&7 here)
    int oa0 = col, oa1 = col + 16;
    int e0 = wid * 32 + col, e1 = e0 + 16;

    f32x4 acc00 = {0.f,0.f,0.f,0.f}, acc01 = {0.f,0.f,0.f,0.f};
    f32x4 acc10 = {0.f,0.f,0.f,0.f}, acc11 = {0.f,0.f,0.f,0.f};
    #pragma unroll
    for (int ks = 0; ks < 4; ++ks) {
        int kb = ks * 64 + lk16;
        short8 a0 = *reinterpret_cast<const short8*>(sm + (((oa0 << 8) + kb) ^ xr));
        short8 a1 = *reinterpret_cast<const short8*>(sm + (((oa1 << 8) + kb) ^ xr));
        short8 b0 = *reinterpret_cast<const short8*>(sm + 8192 + (((e0 << 8) + kb) ^ xr));
        short8 b1 = *reinterpret_cast<const short8*>(sm + 8192 + (((e1 << 8) + kb) ^ xr));
        acc00 = __builtin_amdgcn_mfma_f32_16x16x32_bf16(a0, b0, acc00, 0, 0, 0);
        acc01 = __builtin_amdgcn_mfma_f32_16x16x32_bf16(a0, b1, acc01, 0, 0, 0);
        acc10 = __builtin_amdgcn_mfma_f32_16x16x32_bf16(a1, b0, acc10, 0, 0, 0);
        acc11 = __builtin_amdgcn_mfma_f32_16x16x32_bf16(a1, b1, acc11, 0, 0, 0);
    }
    __syncthreads();   // staging no longer needed; write H over it

    // D layout: col = lane&15, row = (lane>>4)*4 + reg   [m89-verified]
    // H stride 132 (pad 4) -> write banks 2-way (free) instead of 4-way
    float* H = (float*)sm;             // H[32][132] f32, 16.9 KB
    int rowbase = (l >> 4) * 4;
    #pragma unroll
    for (int r4 = 0; r4 < 4; ++r4) {
        int o0 = rowbase + r4, o1 = o0 + 16;
        float bb0 = b_c1[o0], bb1 = b_c1[o1];
        H[o0 * 132 + e0] = acc00[r4] + bb0;
        H[o0 * 132 + e1] = acc01[r4] + bb0;
        H[o1 * 132 + e0] = acc10[r4] + bb1;
        H[o1 * 132 + e1] = acc11[r4] + bb1;
    }
    __syncthreads();

    // pool1
    float* PL = (float*)(sm + 17408);  // 1024 f
    for (int idx = tid; idx < 1024; idx += 256) {
        int o = idx >> 5, h2 = (idx >> 1) & 15, w2 = idx & 1;
        const float* hp = H + o * 132 + h2 * 8 + w2 * 2;
        PL[o * 32 + h2 * 2 + w2] =
            fmaxf(fmaxf(hp[0], hp[1]), fmaxf(hp[4], hp[5]));
    }
    __syncthreads();

    // conv2
    float* C2 = (float*)(sm + 21504);  // 256 f
    {
        int o2 = tid >> 5, pos = tid & 31;
        float a2 = b_c2[o2];
        #pragma unroll 8
        for (int o = 0; o < 32; ++o) a2 += w_c2[o2 * 32 + o] * PL[o * 32 + pos];
        C2[o2 * 32 + pos] = a2;
    }
    __syncthreads();

    // pool2
    float* V = (float*)(sm + 22528);   // 64 f
    if (tid < 64) {
        int o2 = tid >> 3, h3 = tid & 7;
        const float* cp = C2 + o2 * 32 + h3 * 4;
        V[tid] = fmaxf(fmaxf(cp[0], cp[1]), fmaxf(cp[2], cp[3]));
    }
    __syncthreads();

    float* R1 = (float*)(sm + 22784);  // 32 f
    if (tid < 32) {
        float a = b_fc1[tid];
        const float* wr = w_fc1 + tid * 64;
        #pragma unroll 8
        for (int u = 0; u < 64; ++u) a += wr[u] * V[u];
        R1[tid] = fmaxf(a, 0.f);
    }
    __syncthreads();

    float* R2 = (float*)(sm + 22912);  // 8 f
    if (tid < 8) {
        float a = b_fc2[tid];
        #pragma unroll 8
        for (int u = 0; u < 32; ++u) a += w_fc2[tid * 32 + u] * R1[u];
        R2[tid] = fmaxf(a, 0.f);
    }
    __syncthreads();

    if (tid == 0) {
        float a = b_fc3[0];
        #pragma unroll
        for (int u = 0; u < 8; ++u) a += w_fc3[u] * R2[u];
        out[64 + p] = 1.f / (1.f + expf(-a));
    }
}

extern "C" void kernel_launch(void* const* d_in, const int* in_sizes, int n_in,
                              void* d_out, int out_size, void* d_ws, size_t ws_size,
                              hipStream_t stream) {
    const float* x        = (const float*)d_in[0];
    const float* w_conv1d = (const float*)d_in[1];
    const float* b_conv1d = (const float*)d_in[2];
    const float* w_c1     = (const float*)d_in[3];
    const float* b_c1     = (const float*)d_in[4];
    const float* w_c2     = (const float*)d_in[5];
    const float* b_c2     = (const float*)d_in[6];
    const float* w_fc1    = (const float*)d_in[7];
    const float* b_fc1    = (const float*)d_in[8];
    const float* w_fc2    = (const float*)d_in[9];
    const float* b_fc2    = (const float*)d_in[10];
    const float* w_fc3    = (const float*)d_in[11];
    const float* b_fc3    = (const float*)d_in[12];
    const float* w_mlp    = (const float*)d_in[13];
    const float* b_mlp    = (const float*)d_in[14];
    float* out = (float*)d_out;

    char* base = (char*)d_ws;
    unsigned short* xxTf = (unsigned short*)(base);                  // 4 MB
    unsigned short* FTTb = (unsigned short*)(base + 4194304);        // 2 MB
    unsigned short* ALb  = (unsigned short*)(base + 6291456);        // 512 KB
    unsigned short* Wbf  = (unsigned short*)(base + 6815744);        // 320 KB
    float*          Gb   = (float*)(base + 7143424);                 // 1280 B
    float*          part = (float*)(base + 7145472);                 // 1 KB
    // total ~6.8 MB (9 MB proven safe)

    hipLaunchKernelGGL(k_prep, dim3(1025), dim3(256), 0, stream,
                       x, w_conv1d, b_conv1d, w_c1, w_mlp,
                       xxTf, Wbf, Gb, part);
    hipLaunchKernelGGL(k_fgemm, dim3(64, 5, 4), dim3(256), 0, stream,
                       Wbf, xxTf, Gb, FTTb, ALb);
    hipLaunchKernelGGL(k_pairs, dim3(2016), dim3(256), 0, stream,
                       (const char*)FTTb, (const char*)ALb,
                       b_c1, w_c2, b_c2, w_fc1, b_fc1,
                       w_fc2, b_fc2, w_fc3, b_fc3, part, b_mlp, out);
}